// Round 4
// baseline (110.945 us; speedup 1.0000x reference)
//
#include <hip/hip_runtime.h>

#define NB 8
#define LC 512
#define LQ 64
#define DD 256
#define NEG_BIG_F 1e30f

#define TPB 512            // 8 waves -> 2 waves/SIMD (round-1 occupancy, proven)
#define NWAVE 8
#define RPW 2              // rows per wave: one T-pass feeds 2 rows
#define RPB (NWAVE * RPW)  // 16 rows per block
#define BPB (LC / RPB)     // 32 blocks per batch -> grid = 256 (1 block/CU)
#define CNT_OFF (NB * LC * 16)   // per-batch counters right after ws4 (64 KiB)

// Broadcast a float from `lane` to all lanes as a wave-uniform (SGPR) value.
__device__ __forceinline__ float bcastf(float x, int lane) {
  return __uint_as_float((unsigned)__builtin_amdgcn_readlane((int)__float_as_uint(x), lane));
}

__global__ __launch_bounds__(TPB, 2) void fused_kernel(
    const float* __restrict__ context,   // [NB][LC][DD]
    const float* __restrict__ question,  // [NB][LQ][DD]
    const int*   __restrict__ mask,      // [NB][LQ]
    const float* __restrict__ att_w,     // [3*DD]
    const float* __restrict__ att_b,     // [1]
    const float* __restrict__ w_in,      // [DD]
    const float* __restrict__ w_mem,     // [DD]
    float4* __restrict__ ws4,            // [NB*LC] {rowmax, ctx1, U, 0}
    int*    __restrict__ cnt,            // [NB], zeroed by memset each launch
    float4* __restrict__ out4)           // [NB*LC] {c1, U, c1*U, U*H}
{
  // T[c][j ^ (c&7)] = question[b][j][4c..4c+3].
  // Writes: lane=c (fixed j)  -> 8 distinct 16B slots per 128B phase.
  // Reads : lane=j (fixed c)  -> blockwise-XOR perm of consecutive float4s.
  // Both conflict-free.
  __shared__ float4 T[64][64];                   // 64 KiB
  __shared__ float sq_raw[LQ];                   // q-term of score (no bias/mask)
  __shared__ float q1_s[LQ];
  __shared__ float rr[3][NWAVE];                 // tail cross-wave scratch
  __shared__ int   lastv;

  const int tid  = threadIdx.x;
  const int w    = tid >> 6;           // wave 0..7
  const int l    = tid & 63;           // lane
  const int b    = blockIdx.x / BPB;
  const int row0 = (blockIdx.x % BPB) * RPB;
  const int iA   = row0 + w * RPW;     // this wave's first context row
  const int iB   = iA + 1;             // second context row

  // ---- hoisted per-lane loads (lane = d-chunk) ----
  const float4 wc4 = ((const float4*)att_w)[l];
  const float4 wq4 = ((const float4*)(att_w + DD))[l];
  const float4 wp4 = ((const float4*)(att_w + 2 * DD))[l];
  const float4 wi4 = ((const float4*)w_in)[l];
  const float4 wm4 = ((const float4*)w_mem)[l];
  const float4 cA  = ((const float4*)(context + ((size_t)b * LC + iA) * DD))[l];
  const float4 cB  = ((const float4*)(context + ((size_t)b * LC + iB) * DD))[l];

  // ---- staging: instruction k loads ONE full q-row (row j = k*8 + w):
  // 64 lanes x 16B = exactly the 1KiB row -> perfectly coalesced.
  float4 v[8];
#pragma unroll
  for (int k = 0; k < 8; ++k)
    v[k] = ((const float4*)(question + ((size_t)b * LQ + (k * 8 + w)) * DD))[l];
#pragma unroll
  for (int k = 0; k < 8; ++k)
    T[l][(k * 8 + w) ^ (l & 7)] = v[k];

  // per-row partial dot products (lane l holds chunk l's contribution)
  float psq[8], pq1[8];
#pragma unroll
  for (int k = 0; k < 8; ++k) {
    psq[k] = v[k].x*wq4.x + v[k].y*wq4.y + v[k].z*wq4.z + v[k].w*wq4.w;
    pq1[k] = v[k].x*wm4.x + v[k].y*wm4.y + v[k].z*wm4.z + v[k].w*wm4.w;
  }
  // butterfly-reduce all 16 chains together (ILP hides shuffle latency)
#pragma unroll
  for (int off = 32; off > 0; off >>= 1) {
#pragma unroll
    for (int k = 0; k < 8; ++k) {
      psq[k] += __shfl_xor(psq[k], off);
      pq1[k] += __shfl_xor(pq1[k], off);
    }
  }
  if (l == 0) {
#pragma unroll
    for (int k = 0; k < 8; ++k) {
      sq_raw[k * 8 + w] = psq[k];
      q1_s[k * 8 + w]   = pq1[k];
    }
  }

  // ---- this wave's row-local terms (overlap with staging latency) ----
  float4 cpA, cpB;
  cpA.x = cA.x*wp4.x; cpA.y = cA.y*wp4.y; cpA.z = cA.z*wp4.z; cpA.w = cA.w*wp4.w;
  cpB.x = cB.x*wp4.x; cpB.y = cB.y*wp4.y; cpB.z = cB.z*wp4.z; cpB.w = cB.w*wp4.w;
  float scA = cA.x*wc4.x + cA.y*wc4.y + cA.z*wc4.z + cA.w*wc4.w;
  float scB = cB.x*wc4.x + cB.y*wc4.y + cB.z*wc4.z + cB.w*wc4.w;
  float c1A = cA.x*wi4.x + cA.y*wi4.y + cA.z*wi4.z + cA.w*wi4.w;
  float c1B = cB.x*wi4.x + cB.y*wi4.y + cB.z*wi4.z + cB.w*wi4.w;
#pragma unroll
  for (int off = 32; off > 0; off >>= 1) {
    scA += __shfl_xor(scA, off);
    scB += __shfl_xor(scB, off);
    c1A += __shfl_xor(c1A, off);
    c1B += __shfl_xor(c1B, off);
  }

  __syncthreads();

  // ---- main loop: lane l = q-column j; ctx chunk broadcast via readlane.
  // ONE pass over T feeds BOTH rows -> LDS read bytes per row halved.
  float a0 = 0.f, a1 = 0.f, a2 = 0.f, a3 = 0.f;   // row A chains
  float e0 = 0.f, e1 = 0.f, e2 = 0.f, e3 = 0.f;   // row B chains
#pragma unroll
  for (int c = 0; c < 64; ++c) {
    float4 qv = T[c][l ^ (c & 7)];
    a0 += bcastf(cpA.x, c) * qv.x;
    a1 += bcastf(cpA.y, c) * qv.y;
    a2 += bcastf(cpA.z, c) * qv.z;
    a3 += bcastf(cpA.w, c) * qv.w;
    e0 += bcastf(cpB.x, c) * qv.x;
    e1 += bcastf(cpB.y, c) * qv.y;
    e2 += bcastf(cpB.z, c) * qv.z;
    e3 += bcastf(cpB.w, c) * qv.w;
  }

  const float mf   = (float)mask[b * LQ + l];
  const float base = sq_raw[l] + att_b[0] - NEG_BIG_F * (1.0f - mf);
  float sA = (a0 + a1) + (a2 + a3) + scA + base;
  float sB = (e0 + e1) + (e2 + e3) + scB + base;
  const float q1_l = q1_s[l];

  float mA = sA, mB = sB;
#pragma unroll
  for (int off = 32; off > 0; off >>= 1) {
    mA = fmaxf(mA, __shfl_xor(mA, off));
    mB = fmaxf(mB, __shfl_xor(mB, off));
  }
  float pA = __expf(sA - mA);
  float pB = __expf(sB - mB);
  float psA = pA, puA = pA * q1_l;
  float psB = pB, puB = pB * q1_l;
#pragma unroll
  for (int off = 32; off > 0; off >>= 1) {
    psA += __shfl_xor(psA, off);
    puA += __shfl_xor(puA, off);
    psB += __shfl_xor(psB, off);
    puB += __shfl_xor(puB, off);
  }
  if (l == 0) {
    ws4[b * LC + iA] = make_float4(mA, c1A, puA / psA, 0.f);
    ws4[b * LC + iB] = make_float4(mB, c1B, puB / psB, 0.f);
  }

  // ---- last-block-done handshake (canonical threadfence-reduction form) ----
  __threadfence();                       // release: this thread's ws4 stores
  __syncthreads();                       // whole block fenced
  if (tid == 0) {
    const int old = atomicAdd(&cnt[b], 1);
    lastv = (old == BPB - 1);
  }
  __syncthreads();
  if (!lastv) return;
  if (tid == 0) __threadfence();         // acquire side of the atomic
  __syncthreads();

  // ---- batch tail: softmax over row-maxes -> H; write final out ----
  const float4 vA = ws4[b * LC + tid];   // 512 threads = 512 rows
  float mx = vA.x;
#pragma unroll
  for (int off = 32; off > 0; off >>= 1) mx = fmaxf(mx, __shfl_xor(mx, off));
  if (l == 0) rr[0][w] = mx;
  __syncthreads();
  mx = rr[0][0];
#pragma unroll
  for (int k = 1; k < NWAVE; ++k) mx = fmaxf(mx, rr[0][k]);

  const float p = __expf(vA.x - mx);
  float S = p;
  float C = p * vA.y;
#pragma unroll
  for (int off = 32; off > 0; off >>= 1) {
    S += __shfl_xor(S, off);
    C += __shfl_xor(C, off);
  }
  if (l == 0) { rr[1][w] = S; rr[2][w] = C; }
  __syncthreads();
  S = 0.f; C = 0.f;
#pragma unroll
  for (int k = 0; k < NWAVE; ++k) { S += rr[1][k]; C += rr[2][k]; }
  const float H = C / S;

  out4[b * LC + tid] = make_float4(vA.y, vA.z, vA.y * vA.z, vA.z * H);
}

extern "C" void kernel_launch(void* const* d_in, const int* in_sizes, int n_in,
                              void* d_out, int out_size, void* d_ws, size_t ws_size,
                              hipStream_t stream) {
  const float* context  = (const float*)d_in[0];
  const float* question = (const float*)d_in[1];
  const int*   mask     = (const int*)d_in[2];
  const float* att_w    = (const float*)d_in[3];
  const float* att_b    = (const float*)d_in[4];
  const float* w_in     = (const float*)d_in[5];
  const float* w_mem    = (const float*)d_in[6];
  float4* out4 = (float4*)d_out;
  float4* ws4  = (float4*)d_ws;
  int*    cnt  = (int*)((char*)d_ws + CNT_OFF);

  // zero the 8 per-batch arrival counters (graph-capturable, poison-independent)
  hipMemsetAsync(cnt, 0, NB * sizeof(int), stream);

  fused_kernel<<<dim3(NB * BPB), dim3(TPB), 0, stream>>>(
      context, question, mask, att_w, att_b, w_in, w_mem, ws4, cnt, out4);
}

// Round 5
// 75.960 us; speedup vs baseline: 1.4606x; 1.4606x over previous
//
#include <hip/hip_runtime.h>

#define NB 8
#define LC 512
#define LQ 64
#define DD 256
#define NEG_BIG_F 1e30f

#define TPB 512            // 8 waves -> 2 waves/SIMD (proven best occupancy)
#define NWAVE 8
#define RPW 2              // rows per wave: one T-pass feeds 2 rows
#define RPB (NWAVE * RPW)  // 16 rows per block
#define BPB (LC / RPB)     // 32 blocks per batch -> grid = 256 (1 block/CU)

// Broadcast a float from `lane` to all lanes as a wave-uniform (SGPR) value.
__device__ __forceinline__ float bcastf(float x, int lane) {
  return __uint_as_float((unsigned)__builtin_amdgcn_readlane((int)__float_as_uint(x), lane));
}

// Phase 1: per-row {rowmax, ctx1, U} -> written into out4 (aliased as scratch).
__global__ __launch_bounds__(TPB, 2) void rows_kernel(
    const float* __restrict__ context,   // [NB][LC][DD]
    const float* __restrict__ question,  // [NB][LQ][DD]
    const int*   __restrict__ mask,      // [NB][LQ]
    const float* __restrict__ att_w,     // [3*DD]
    const float* __restrict__ att_b,     // [1]
    const float* __restrict__ w_in,      // [DD]
    const float* __restrict__ w_mem,     // [DD]
    float4* __restrict__ ws4)            // = out4: [NB*LC] {rowmax, ctx1, U, 0}
{
  // T[c][j ^ (c&7)] = question[b][j][4c..4c+3].
  // Writes: lane=c (fixed j)  -> 8 distinct 16B slots per 128B phase.
  // Reads : lane=j (fixed c)  -> blockwise-XOR perm of consecutive float4s.
  // Both conflict-free.
  __shared__ float4 T[64][64];                   // 64 KiB
  __shared__ float sq_raw[LQ];                   // q-term of score (no bias/mask)
  __shared__ float q1_s[LQ];

  const int tid  = threadIdx.x;
  const int w    = tid >> 6;           // wave 0..7
  const int l    = tid & 63;           // lane
  const int b    = blockIdx.x / BPB;
  const int row0 = (blockIdx.x % BPB) * RPB;
  const int iA   = row0 + w * RPW;     // this wave's first context row
  const int iB   = iA + 1;             // second context row

  // ---- hoisted per-lane loads (lane = d-chunk) ----
  const float4 wc4 = ((const float4*)att_w)[l];
  const float4 wq4 = ((const float4*)(att_w + DD))[l];
  const float4 wp4 = ((const float4*)(att_w + 2 * DD))[l];
  const float4 wi4 = ((const float4*)w_in)[l];
  const float4 wm4 = ((const float4*)w_mem)[l];
  const float4 cA  = ((const float4*)(context + ((size_t)b * LC + iA) * DD))[l];
  const float4 cB  = ((const float4*)(context + ((size_t)b * LC + iB) * DD))[l];

  // ---- staging: instruction k loads ONE full q-row (row j = k*8 + w):
  // 64 lanes x 16B = exactly the 1KiB row -> perfectly coalesced.
  float4 v[8];
#pragma unroll
  for (int k = 0; k < 8; ++k)
    v[k] = ((const float4*)(question + ((size_t)b * LQ + (k * 8 + w)) * DD))[l];
#pragma unroll
  for (int k = 0; k < 8; ++k)
    T[l][(k * 8 + w) ^ (l & 7)] = v[k];

  // per-row partial dot products (lane l holds chunk l's contribution)
  float psq[8], pq1[8];
#pragma unroll
  for (int k = 0; k < 8; ++k) {
    psq[k] = v[k].x*wq4.x + v[k].y*wq4.y + v[k].z*wq4.z + v[k].w*wq4.w;
    pq1[k] = v[k].x*wm4.x + v[k].y*wm4.y + v[k].z*wm4.z + v[k].w*wm4.w;
  }
  // butterfly-reduce all 16 chains together (ILP hides shuffle latency)
#pragma unroll
  for (int off = 32; off > 0; off >>= 1) {
#pragma unroll
    for (int k = 0; k < 8; ++k) {
      psq[k] += __shfl_xor(psq[k], off);
      pq1[k] += __shfl_xor(pq1[k], off);
    }
  }
  if (l == 0) {
#pragma unroll
    for (int k = 0; k < 8; ++k) {
      sq_raw[k * 8 + w] = psq[k];
      q1_s[k * 8 + w]   = pq1[k];
    }
  }

  // ---- this wave's row-local terms (overlap with staging latency) ----
  float4 cpA, cpB;
  cpA.x = cA.x*wp4.x; cpA.y = cA.y*wp4.y; cpA.z = cA.z*wp4.z; cpA.w = cA.w*wp4.w;
  cpB.x = cB.x*wp4.x; cpB.y = cB.y*wp4.y; cpB.z = cB.z*wp4.z; cpB.w = cB.w*wp4.w;
  float scA = cA.x*wc4.x + cA.y*wc4.y + cA.z*wc4.z + cA.w*wc4.w;
  float scB = cB.x*wc4.x + cB.y*wc4.y + cB.z*wc4.z + cB.w*wc4.w;
  float c1A = cA.x*wi4.x + cA.y*wi4.y + cA.z*wi4.z + cA.w*wi4.w;
  float c1B = cB.x*wi4.x + cB.y*wi4.y + cB.z*wi4.z + cB.w*wi4.w;
#pragma unroll
  for (int off = 32; off > 0; off >>= 1) {
    scA += __shfl_xor(scA, off);
    scB += __shfl_xor(scB, off);
    c1A += __shfl_xor(c1A, off);
    c1B += __shfl_xor(c1B, off);
  }

  __syncthreads();

  // ---- main loop: lane l = q-column j; ctx chunk broadcast via readlane.
  // ONE pass over T feeds BOTH rows -> LDS read bytes per row halved.
  float a0 = 0.f, a1 = 0.f, a2 = 0.f, a3 = 0.f;   // row A chains
  float e0 = 0.f, e1 = 0.f, e2 = 0.f, e3 = 0.f;   // row B chains
#pragma unroll
  for (int c = 0; c < 64; ++c) {
    float4 qv = T[c][l ^ (c & 7)];
    a0 += bcastf(cpA.x, c) * qv.x;
    a1 += bcastf(cpA.y, c) * qv.y;
    a2 += bcastf(cpA.z, c) * qv.z;
    a3 += bcastf(cpA.w, c) * qv.w;
    e0 += bcastf(cpB.x, c) * qv.x;
    e1 += bcastf(cpB.y, c) * qv.y;
    e2 += bcastf(cpB.z, c) * qv.z;
    e3 += bcastf(cpB.w, c) * qv.w;
  }

  const float mf   = (float)mask[b * LQ + l];
  const float base = sq_raw[l] + att_b[0] - NEG_BIG_F * (1.0f - mf);
  float sA = (a0 + a1) + (a2 + a3) + scA + base;
  float sB = (e0 + e1) + (e2 + e3) + scB + base;
  const float q1_l = q1_s[l];

  float mA = sA, mB = sB;
#pragma unroll
  for (int off = 32; off > 0; off >>= 1) {
    mA = fmaxf(mA, __shfl_xor(mA, off));
    mB = fmaxf(mB, __shfl_xor(mB, off));
  }
  float pA = __expf(sA - mA);
  float pB = __expf(sB - mB);
  float psA = pA, puA = pA * q1_l;
  float psB = pB, puB = pB * q1_l;
#pragma unroll
  for (int off = 32; off > 0; off >>= 1) {
    psA += __shfl_xor(psA, off);
    puA += __shfl_xor(puA, off);
    psB += __shfl_xor(psB, off);
    puB += __shfl_xor(puB, off);
  }
  if (l == 0) {
    ws4[b * LC + iA] = make_float4(mA, c1A, puA / psA, 0.f);
    ws4[b * LC + iB] = make_float4(mB, c1B, puB / psB, 0.f);
  }
}

// Phase 2: in-place rewrite of out4. Each thread reads ONLY its own row and
// writes ONLY its own row -> no cross-thread hazard from aliasing.
__global__ __launch_bounds__(512) void batch_kernel(
    float4* __restrict__ out4)           // in: {m, c1, U, 0}; out: {c1,U,c1U,UH}
{
  const int b  = blockIdx.x;
  const int t  = threadIdx.x;           // row i
  const int gi = b * LC + t;
  const float4 v = out4[gi];
  const float m = v.x, c1 = v.y, U = v.z;

  const int w = t >> 6, l = t & 63;
  __shared__ float rmax[8], rs[8], rc[8];

  float mx = m;
#pragma unroll
  for (int off = 32; off > 0; off >>= 1) mx = fmaxf(mx, __shfl_xor(mx, off));
  if (l == 0) rmax[w] = mx;
  __syncthreads();
  mx = rmax[0];
#pragma unroll
  for (int k = 1; k < 8; ++k) mx = fmaxf(mx, rmax[k]);

  float p  = __expf(m - mx);
  float ps = p;
  float pc = p * c1;
#pragma unroll
  for (int off = 32; off > 0; off >>= 1) {
    ps += __shfl_xor(ps, off);
    pc += __shfl_xor(pc, off);
  }
  if (l == 0) { rs[w] = ps; rc[w] = pc; }
  __syncthreads();
  float S = 0.f, C = 0.f;
#pragma unroll
  for (int k = 0; k < 8; ++k) { S += rs[k]; C += rc[k]; }

  const float H = C / S;
  out4[gi] = make_float4(c1, U, c1 * U, U * H);
}

extern "C" void kernel_launch(void* const* d_in, const int* in_sizes, int n_in,
                              void* d_out, int out_size, void* d_ws, size_t ws_size,
                              hipStream_t stream) {
  const float* context  = (const float*)d_in[0];
  const float* question = (const float*)d_in[1];
  const int*   mask     = (const int*)d_in[2];
  const float* att_w    = (const float*)d_in[3];
  const float* att_b    = (const float*)d_in[4];
  const float* w_in     = (const float*)d_in[5];
  const float* w_mem    = (const float*)d_in[6];
  float4* out4 = (float4*)d_out;
  (void)d_ws; (void)ws_size;            // workspace deliberately untouched

  rows_kernel<<<dim3(NB * BPB), dim3(TPB), 0, stream>>>(
      context, question, mask, att_w, att_b, w_in, w_mem, out4);
  batch_kernel<<<dim3(NB), dim3(512), 0, stream>>>(out4);
}

// Round 6
// 73.568 us; speedup vs baseline: 1.5081x; 1.0325x over previous
//
#include <hip/hip_runtime.h>

#define NB 8
#define LC 512
#define LQ 64
#define DD 256
#define NEG_BIG_F 1e30f

#define TPB 512            // 8 waves -> 2 waves/SIMD (proven best occupancy)
#define NWAVE 8
#define RPW 2              // rows per wave: one T-pass feeds 2 rows
#define RPB (NWAVE * RPW)  // 16 rows per block
#define BPB (LC / RPB)    // 32 blocks per batch -> grid = 256 (1 block/CU)

// Broadcast a float from `lane` to all lanes as a wave-uniform (SGPR) value.
__device__ __forceinline__ float bcastf(float x, int lane) {
  return __uint_as_float((unsigned)__builtin_amdgcn_readlane((int)__float_as_uint(x), lane));
}

// Wave64 sum-reduction entirely on the VALU pipe (rocPRIM DPP pattern):
// row_shr 1/2/4/8 then row_bcast:15 / row_bcast:31. bound_ctrl=true zero-fills
// invalid lanes (identity for +). Total lands in lane 63. ZERO DS-pipe ops.
__device__ __forceinline__ float dpp_sum(float x) {
  x += __uint_as_float((unsigned)__builtin_amdgcn_update_dpp(
      0, (int)__float_as_uint(x), 0x111, 0xf, 0xf, true));   // row_shr:1
  x += __uint_as_float((unsigned)__builtin_amdgcn_update_dpp(
      0, (int)__float_as_uint(x), 0x112, 0xf, 0xf, true));   // row_shr:2
  x += __uint_as_float((unsigned)__builtin_amdgcn_update_dpp(
      0, (int)__float_as_uint(x), 0x114, 0xf, 0xf, true));   // row_shr:4
  x += __uint_as_float((unsigned)__builtin_amdgcn_update_dpp(
      0, (int)__float_as_uint(x), 0x118, 0xf, 0xf, true));   // row_shr:8
  x += __uint_as_float((unsigned)__builtin_amdgcn_update_dpp(
      0, (int)__float_as_uint(x), 0x142, 0xf, 0xf, true));   // row_bcast:15
  x += __uint_as_float((unsigned)__builtin_amdgcn_update_dpp(
      0, (int)__float_as_uint(x), 0x143, 0xf, 0xf, true));   // row_bcast:31
  return x;  // lane 63 holds the full 64-lane sum
}

// Phase 1: per-row {rowmax, ctx1, U} -> written into out4 (aliased as scratch).
__global__ __launch_bounds__(TPB, 2) void rows_kernel(
    const float* __restrict__ context,   // [NB][LC][DD]
    const float* __restrict__ question,  // [NB][LQ][DD]
    const int*   __restrict__ mask,      // [NB][LQ]
    const float* __restrict__ att_w,     // [3*DD]
    const float* __restrict__ att_b,     // [1]
    const float* __restrict__ w_in,      // [DD]
    const float* __restrict__ w_mem,     // [DD]
    float4* __restrict__ ws4)            // = out4: [NB*LC] {rowmax, ctx1, U, 0}
{
  // T[c][j ^ (c&7)] = question[b][j][4c..4c+3].
  // Writes: lane=c (fixed j)  -> 8 distinct 16B slots per 128B phase.
  // Reads : lane=j (fixed c)  -> blockwise-XOR perm of consecutive float4s.
  // Both conflict-free.
  __shared__ float4 T[64][64];                   // 64 KiB
  __shared__ float sq_raw[LQ];                   // q-term of score (no bias/mask)
  __shared__ float q1_s[LQ];

  const int tid  = threadIdx.x;
  const int w    = tid >> 6;           // wave 0..7
  const int l    = tid & 63;           // lane
  const int b    = blockIdx.x / BPB;
  const int row0 = (blockIdx.x % BPB) * RPB;
  const int iA   = row0 + w * RPW;     // this wave's first context row
  const int iB   = iA + 1;             // second context row

  // ---- hoisted per-lane loads (lane = d-chunk) ----
  const float4 wc4 = ((const float4*)att_w)[l];
  const float4 wq4 = ((const float4*)(att_w + DD))[l];
  const float4 wp4 = ((const float4*)(att_w + 2 * DD))[l];
  const float4 wi4 = ((const float4*)w_in)[l];
  const float4 wm4 = ((const float4*)w_mem)[l];
  const float4 cA  = ((const float4*)(context + ((size_t)b * LC + iA) * DD))[l];
  const float4 cB  = ((const float4*)(context + ((size_t)b * LC + iB) * DD))[l];

  // ---- staging: instruction k loads ONE full q-row (row j = k*8 + w):
  // 64 lanes x 16B = exactly the 1KiB row -> perfectly coalesced.
  float4 v[8];
#pragma unroll
  for (int k = 0; k < 8; ++k)
    v[k] = ((const float4*)(question + ((size_t)b * LQ + (k * 8 + w)) * DD))[l];
#pragma unroll
  for (int k = 0; k < 8; ++k)
    T[l][(k * 8 + w) ^ (l & 7)] = v[k];

  // per-row partial dot products (lane l holds chunk l's contribution);
  // reduce on the VALU pipe (DPP) -> keeps the DS pipe free for T traffic.
  float psq[8], pq1[8];
#pragma unroll
  for (int k = 0; k < 8; ++k) {
    psq[k] = dpp_sum(v[k].x*wq4.x + v[k].y*wq4.y + v[k].z*wq4.z + v[k].w*wq4.w);
    pq1[k] = dpp_sum(v[k].x*wm4.x + v[k].y*wm4.y + v[k].z*wm4.z + v[k].w*wm4.w);
  }
  if (l == 63) {
#pragma unroll
    for (int k = 0; k < 8; ++k) {
      sq_raw[k * 8 + w] = psq[k];
      q1_s[k * 8 + w]   = pq1[k];
    }
  }

  // ---- this wave's row-local terms (overlap with staging latency) ----
  float4 cpA, cpB;
  cpA.x = cA.x*wp4.x; cpA.y = cA.y*wp4.y; cpA.z = cA.z*wp4.z; cpA.w = cA.w*wp4.w;
  cpB.x = cB.x*wp4.x; cpB.y = cB.y*wp4.y; cpB.z = cB.z*wp4.z; cpB.w = cB.w*wp4.w;
  // sums in lane 63; scA/scB needed by all lanes -> readlane-broadcast
  const float scA = bcastf(dpp_sum(cA.x*wc4.x + cA.y*wc4.y + cA.z*wc4.z + cA.w*wc4.w), 63);
  const float scB = bcastf(dpp_sum(cB.x*wc4.x + cB.y*wc4.y + cB.z*wc4.z + cB.w*wc4.w), 63);
  // c1A/c1B only consumed by the lane-63 store
  const float c1A = dpp_sum(cA.x*wi4.x + cA.y*wi4.y + cA.z*wi4.z + cA.w*wi4.w);
  const float c1B = dpp_sum(cB.x*wi4.x + cB.y*wi4.y + cB.z*wi4.z + cB.w*wi4.w);

  __syncthreads();

  // ---- main loop: lane l = q-column j; ctx chunk broadcast via readlane.
  // ONE pass over T feeds BOTH rows -> LDS read bytes per row halved.
  float a0 = 0.f, a1 = 0.f, a2 = 0.f, a3 = 0.f;   // row A chains
  float e0 = 0.f, e1 = 0.f, e2 = 0.f, e3 = 0.f;   // row B chains
#pragma unroll
  for (int c = 0; c < 64; ++c) {
    float4 qv = T[c][l ^ (c & 7)];
    a0 += bcastf(cpA.x, c) * qv.x;
    a1 += bcastf(cpA.y, c) * qv.y;
    a2 += bcastf(cpA.z, c) * qv.z;
    a3 += bcastf(cpA.w, c) * qv.w;
    e0 += bcastf(cpB.x, c) * qv.x;
    e1 += bcastf(cpB.y, c) * qv.y;
    e2 += bcastf(cpB.z, c) * qv.z;
    e3 += bcastf(cpB.w, c) * qv.w;
  }

  const float mf   = (float)mask[b * LQ + l];
  const float base = sq_raw[l] + att_b[0] - NEG_BIG_F * (1.0f - mf);
  float sA = (a0 + a1) + (a2 + a3) + scA + base;
  float sB = (e0 + e1) + (e2 + e3) + scB + base;
  const float q1_l = q1_s[l];

  // max must reach ALL lanes (exp argument) and zero-fill is wrong for max
  // with -1e30 masked scores -> keep the shfl butterfly here.
  float mA = sA, mB = sB;
#pragma unroll
  for (int off = 32; off > 0; off >>= 1) {
    mA = fmaxf(mA, __shfl_xor(mA, off));
    mB = fmaxf(mB, __shfl_xor(mB, off));
  }
  const float pA = __expf(sA - mA);
  const float pB = __expf(sB - mB);
  // sums -> DPP (lane 63), which is also the storing lane
  const float psA = dpp_sum(pA), puA = dpp_sum(pA * q1_l);
  const float psB = dpp_sum(pB), puB = dpp_sum(pB * q1_l);
  if (l == 63) {
    ws4[b * LC + iA] = make_float4(mA, c1A, puA / psA, 0.f);
    ws4[b * LC + iB] = make_float4(mB, c1B, puB / psB, 0.f);
  }
}

// Phase 2: in-place rewrite of out4. Each thread reads ONLY its own row and
// writes ONLY its own row -> no cross-thread hazard from aliasing.
__global__ __launch_bounds__(512) void batch_kernel(
    float4* __restrict__ out4)           // in: {m, c1, U, 0}; out: {c1,U,c1U,UH}
{
  const int b  = blockIdx.x;
  const int t  = threadIdx.x;           // row i
  const int gi = b * LC + t;
  const float4 v = out4[gi];
  const float m = v.x, c1 = v.y, U = v.z;

  const int w = t >> 6, l = t & 63;
  __shared__ float rmax[8], rs[8], rc[8];

  float mx = m;
#pragma unroll
  for (int off = 32; off > 0; off >>= 1) mx = fmaxf(mx, __shfl_xor(mx, off));
  if (l == 0) rmax[w] = mx;
  __syncthreads();
  mx = rmax[0];
#pragma unroll
  for (int k = 1; k < 8; ++k) mx = fmaxf(mx, rmax[k]);

  float p  = __expf(m - mx);
  float ps = p;
  float pc = p * c1;
#pragma unroll
  for (int off = 32; off > 0; off >>= 1) {
    ps += __shfl_xor(ps, off);
    pc += __shfl_xor(pc, off);
  }
  if (l == 0) { rs[w] = ps; rc[w] = pc; }
  __syncthreads();
  float S = 0.f, C = 0.f;
#pragma unroll
  for (int k = 0; k < 8; ++k) { S += rs[k]; C += rc[k]; }

  const float H = C / S;
  out4[gi] = make_float4(c1, U, c1 * U, U * H);
}

extern "C" void kernel_launch(void* const* d_in, const int* in_sizes, int n_in,
                              void* d_out, int out_size, void* d_ws, size_t ws_size,
                              hipStream_t stream) {
  const float* context  = (const float*)d_in[0];
  const float* question = (const float*)d_in[1];
  const int*   mask     = (const int*)d_in[2];
  const float* att_w    = (const float*)d_in[3];
  const float* att_b    = (const float*)d_in[4];
  const float* w_in     = (const float*)d_in[5];
  const float* w_mem    = (const float*)d_in[6];
  float4* out4 = (float4*)d_out;
  (void)d_ws; (void)ws_size;            // workspace deliberately untouched

  rows_kernel<<<dim3(NB * BPB), dim3(TPB), 0, stream>>>(
      context, question, mask, att_w, att_b, w_in, w_mem, out4);
  batch_kernel<<<dim3(NB), dim3(512), 0, stream>>>(out4);
}